// Round 3
// baseline (1070.329 us; speedup 1.0000x reference)
//
#include <hip/hip_runtime.h>
#include <hip/hip_bf16.h>

// OnlineLayer: res-LN + conv + per-partition graph aggregation (the big GEMM vs
// A: 3x8192x8192 fp32 = 805MB, streamed once -> HBM-bound ~128us floor) + FIFO
// step + LN/ReLU epilogue.
//
// R3 = R2 resubmitted (R2 bench died on container acquisition; no data).
// R2 change: k2 drops LDS + barriers entirely. R0 (drain-everything) and R1
// (counted-vmcnt 3-buffer) timed identically (~500us, 1.6TB/s on an 805MB
// stream) -> the limiter is the global_load_lds + per-chunk-barrier structure
// itself (block-wide lockstep, ~6KB/wave in flight gated per chunk), not the
// waitcnt schedule. New k2: each wave loads its MFMA B-frag straight to
// registers (16x global_load_dword per lane; 4x64B contiguous segments per
// instr -> same cache-line footprint as staged version), packs f32->bf16 with
// the same v_perm truncation, free-runs with no __syncthreads. No LDS -> 4
// blocks/CU, 16 independent waves/CU; outstanding-bytes >> BDP -> BW-bound.
//
// ws layout (bytes):
//   [0, 1572864)           h bf16       (96 x 8192)
//   [1572864, 18350080)    y_part f32   (16 x 32 x 8192) split-K partials
//   [18350080, 19398656)   agg f32      (32 x 8192)
//   [19398656, 20447232)   res f32      (32 x 8192)
//   [20447232, 20447488)   res_part f32 (32 x {sum, sumsq})
//   [20447488, 20449536)   agg_part f32 (256 x {sum, sumsq})

#define PP 3
#define CIN 64
#define COUT 32
#define VV 8192
#define EPSL 1e-5f
#define SPLITK 16

typedef short v8s __attribute__((ext_vector_type(8)));
typedef float v4f __attribute__((ext_vector_type(4)));

// ---------------- block reduce (2 values) + single store ----------------
__device__ __forceinline__ void block_reduce2_store(float s1, float s2,
                                                    float* dst) {
  #pragma unroll
  for (int off = 32; off > 0; off >>= 1) {
    s1 += __shfl_down(s1, off, 64);
    s2 += __shfl_down(s2, off, 64);
  }
  __shared__ float r1[4], r2[4];
  int lane = threadIdx.x & 63, wv = threadIdx.x >> 6;
  if (lane == 0) { r1[wv] = s1; r2[wv] = s2; }
  __syncthreads();
  if (threadIdx.x == 0) {
    dst[0] = r1[0] + r1[1] + r1[2] + r1[3];
    dst[1] = r2[0] + r2[1] + r2[2] + r2[3];
  }
}

// ---------------- K1: convs (h bf16, res f32) + res stat partials ----------------
// grid (32, 4), block 256. og 0..2 -> h rows og*32..og*32+31 ; og 3 -> res.
__global__ __launch_bounds__(256) void k1_conv(
    const float* __restrict__ x, const float* __restrict__ conv_w,
    const float* __restrict__ conv_b, const float* __restrict__ res_w,
    __hip_bfloat16* __restrict__ h, float* __restrict__ res,
    float* __restrict__ res_part) {
  int v = blockIdx.x * 256 + threadIdx.x;
  int og = blockIdx.y;
  float xr[CIN];
  #pragma unroll
  for (int c = 0; c < CIN; ++c) xr[c] = x[c * VV + v];

  if (og < 3) {
    for (int i = 0; i < 32; ++i) {
      int o = og * 32 + i;
      float acc = conv_b[o];
      #pragma unroll
      for (int c = 0; c < CIN; ++c) acc = fmaf(conv_w[o * CIN + c], xr[c], acc);
      h[o * VV + v] = __float2bfloat16(acc);
    }
  } else {
    float s1 = 0.f, s2 = 0.f;
    for (int o = 0; o < COUT; ++o) {
      float acc = 0.f;
      #pragma unroll
      for (int c = 0; c < CIN; ++c) acc = fmaf(res_w[o * CIN + c], xr[c], acc);
      res[o * VV + v] = acc;
      s1 += acc; s2 += acc * acc;
    }
    block_reduce2_store(s1, s2, &res_part[blockIdx.x * 2]);
  }
}

// ---------------- K2: y_part[kb] = h @ A slice, register-direct ----------------
// M=32 (c), per-wave N=32 (2x16), per-block N tile 128, split-K 16, K-chunk 32.
// B-frag (KxN=32x16) lane layout: lane l holds B[k=(l>>4)*8+j][n=l&15], j=0..7.
// Per chunk per lane: 16 dword loads of A (per instr: quad -> 4 rows x 64B
// contiguous, nt=0/1 halves of the same 128B line -> full line use), 2x16B h
// loads (L2-resident), 8 v_perm bf16 packs, 4 MFMA. No LDS, no barriers.
#define TN 128
#define KC 32
#define CHUNKS 48

__global__ __launch_bounds__(256, 4) void k2_gemm(
    const float* __restrict__ A, const __hip_bfloat16* __restrict__ h,
    float* __restrict__ y_part) {
  const int tid = threadIdx.x;
  const int wv = tid >> 6, lane = tid & 63;
  const int quad = lane >> 4, l15 = lane & 15;
  const int wbase = blockIdx.x * TN;
  const int kbase = blockIdx.y * (KC * CHUNKS);
  const int col0 = wbase + wv * 32 + l15;  // nt=0 column for this lane

  v4f acc[2][2] = {};

  for (int c = 0; c < CHUNKS; ++c) {
    int kk = kbase + c * KC;
    int p = kk >> 13, v0 = kk & (VV - 1);

    const __hip_bfloat16* hp =
        h + (size_t)(p * COUT + l15) * VV + v0 + quad * 8;
    v8s hf0 = *(const v8s*)hp;             // A-frag rows l15 (m 0..15)
    v8s hf1 = *(const v8s*)(hp + 16 * VV); // A-frag rows l15+16 (m 16..31)

    const float* Ap = A + ((size_t)p << 26) + (size_t)(v0 + quad * 8) * VV;
    float a0[8], a1[8];
    #pragma unroll
    for (int j = 0; j < 8; ++j) {
      a0[j] = Ap[(size_t)j * VV + col0];        // nt=0: col0
      a1[j] = Ap[(size_t)j * VV + col0 + 16];   // nt=1: col0+16
    }

    union { unsigned u[4]; v8s s; } b0, b1;
    #pragma unroll
    for (int t = 0; t < 4; ++t) {
      // pack hi16(f_{2t+1}) : hi16(f_{2t})  (bf16 truncation, low half = even j)
      b0.u[t] = __builtin_amdgcn_perm(__float_as_uint(a0[2 * t + 1]),
                                      __float_as_uint(a0[2 * t]), 0x07060302u);
      b1.u[t] = __builtin_amdgcn_perm(__float_as_uint(a1[2 * t + 1]),
                                      __float_as_uint(a1[2 * t]), 0x07060302u);
    }

    acc[0][0] = __builtin_amdgcn_mfma_f32_16x16x32_bf16(hf0, b0.s, acc[0][0], 0, 0, 0);
    acc[1][0] = __builtin_amdgcn_mfma_f32_16x16x32_bf16(hf1, b0.s, acc[1][0], 0, 0, 0);
    acc[0][1] = __builtin_amdgcn_mfma_f32_16x16x32_bf16(hf0, b1.s, acc[0][1], 0, 0, 0);
    acc[1][1] = __builtin_amdgcn_mfma_f32_16x16x32_bf16(hf1, b1.s, acc[1][1], 0, 0, 0);
  }

  // C/D: col(w)=lane&15, row(c)=(lane>>4)*4+reg  [m89/m91]
  float* yp = y_part + (size_t)blockIdx.y * COUT * VV;
  #pragma unroll
  for (int mt = 0; mt < 2; ++mt)
    #pragma unroll
    for (int nt = 0; nt < 2; ++nt)
      #pragma unroll
      for (int r = 0; r < 4; ++r) {
        int crow = mt * 16 + quad * 4 + r;
        int w = wbase + wv * 32 + nt * 16 + l15;
        yp[(size_t)crow * VV + w] = acc[mt][nt][r];
      }
}

// ---------------- K3: agg = acc + sum_k y_part[k] - fifo + stat partials ----------------
__global__ __launch_bounds__(256) void k3_agg(
    const float* __restrict__ acc_slot, const float* __restrict__ fifo,
    const float* __restrict__ y_part, float* __restrict__ agg,
    float* __restrict__ agg_part) {
  int i = blockIdx.x * 256 + threadIdx.x;  // float4 index (65536 total)
  float4 s = ((const float4*)y_part)[i];
  #pragma unroll
  for (int kb = 1; kb < SPLITK; ++kb) {
    float4 t = ((const float4*)(y_part + (size_t)kb * COUT * VV))[i];
    s.x += t.x; s.y += t.y; s.z += t.z; s.w += t.w;
  }
  float4 av = ((const float4*)acc_slot)[i];
  float4 fv = ((const float4*)fifo)[i];
  float4 g;
  g.x = av.x + s.x - fv.x;
  g.y = av.y + s.y - fv.y;
  g.z = av.z + s.z - fv.z;
  g.w = av.w + s.w - fv.w;
  ((float4*)agg)[i] = g;
  float s1 = g.x + g.y + g.z + g.w;
  float s2 = g.x * g.x + g.y * g.y + g.z * g.z + g.w * g.w;
  block_reduce2_store(s1, s2, &agg_part[blockIdx.x * 2]);
}

// ---------------- K4: reduce partials; out = relu(relu(LN(agg)) + LN(res)) ----------------
__global__ __launch_bounds__(256) void k4_final(
    const float* __restrict__ agg, const float* __restrict__ res,
    const float* __restrict__ ln_w, const float* __restrict__ ln_b,
    const float* __restrict__ res_ln_w, const float* __restrict__ res_ln_b,
    const float* __restrict__ res_part, const float* __restrict__ agg_part,
    float* __restrict__ out) {
  __shared__ float sf[4];
  if (threadIdx.x < 64) {
    int lane = threadIdx.x;
    float a1 = 0.f, a2 = 0.f;
    #pragma unroll
    for (int j = 0; j < 4; ++j) {
      a1 += agg_part[2 * (lane + 64 * j)];
      a2 += agg_part[2 * (lane + 64 * j) + 1];
    }
    float r1 = 0.f, r2 = 0.f;
    if (lane < 32) { r1 = res_part[2 * lane]; r2 = res_part[2 * lane + 1]; }
    #pragma unroll
    for (int off = 32; off > 0; off >>= 1) {
      a1 += __shfl_down(a1, off, 64);
      a2 += __shfl_down(a2, off, 64);
      r1 += __shfl_down(r1, off, 64);
      r2 += __shfl_down(r2, off, 64);
    }
    if (lane == 0) {
      const float inv_n = 1.0f / (COUT * VV);
      float mr = r1 * inv_n;
      float vr = r2 * inv_n - mr * mr;
      float ma = a1 * inv_n;
      float va = a2 * inv_n - ma * ma;
      sf[0] = mr; sf[1] = rsqrtf(vr + EPSL);
      sf[2] = ma; sf[3] = rsqrtf(va + EPSL);
    }
  }
  __syncthreads();
  const float mr = sf[0], rsr = sf[1], ma = sf[2], rsa = sf[3];

  int i = blockIdx.x * 256 + threadIdx.x;
  float4 g = ((const float4*)agg)[i];
  float4 r = ((const float4*)res)[i];
  float4 w1 = ((const float4*)ln_w)[i], b1 = ((const float4*)ln_b)[i];
  float4 w2 = ((const float4*)res_ln_w)[i], b2 = ((const float4*)res_ln_b)[i];
  float4 o;
  o.x = fmaxf(fmaxf((g.x - ma) * rsa * w1.x + b1.x, 0.f) + (r.x - mr) * rsr * w2.x + b2.x, 0.f);
  o.y = fmaxf(fmaxf((g.y - ma) * rsa * w1.y + b1.y, 0.f) + (r.y - mr) * rsr * w2.y + b2.y, 0.f);
  o.z = fmaxf(fmaxf((g.z - ma) * rsa * w1.z + b1.z, 0.f) + (r.z - mr) * rsr * w2.z + b2.z, 0.f);
  o.w = fmaxf(fmaxf((g.w - ma) * rsa * w1.w + b1.w, 0.f) + (r.w - mr) * rsr * w2.w + b2.w, 0.f);
  ((float4*)out)[i] = o;
}

extern "C" void kernel_launch(void* const* d_in, const int* in_sizes, int n_in,
                              void* d_out, int out_size, void* d_ws, size_t ws_size,
                              hipStream_t stream) {
  const float* x        = (const float*)d_in[0];
  const float* A        = (const float*)d_in[1];
  const float* conv_w   = (const float*)d_in[2];
  const float* conv_b   = (const float*)d_in[3];
  const float* fifo     = (const float*)d_in[4];
  const float* acc_slot = (const float*)d_in[5];
  const float* ln_w     = (const float*)d_in[6];
  const float* ln_b     = (const float*)d_in[7];
  const float* res_w    = (const float*)d_in[8];
  const float* res_ln_w = (const float*)d_in[9];
  const float* res_ln_b = (const float*)d_in[10];
  float* out = (float*)d_out;

  char* ws = (char*)d_ws;
  __hip_bfloat16* h  = (__hip_bfloat16*)ws;
  float* y_part   = (float*)(ws + 1572864);
  float* agg      = (float*)(ws + 18350080);
  float* res      = (float*)(ws + 19398656);
  float* res_part = (float*)(ws + 20447232);
  float* agg_part = (float*)(ws + 20447488);

  k1_conv<<<dim3(32, 4), 256, 0, stream>>>(x, conv_w, conv_b, res_w, h, res, res_part);
  k2_gemm<<<dim3(VV / TN, SPLITK), 256, 0, stream>>>(A, h, y_part);
  k3_agg<<<256, 256, 0, stream>>>(acc_slot, fifo, y_part, agg, agg_part);
  k4_final<<<256, 256, 0, stream>>>(agg, res, ln_w, ln_b, res_ln_w, res_ln_b,
                                    res_part, agg_part, out);
}